// Round 6
// baseline (100.645 us; speedup 1.0000x reference)
//
#include <hip/hip_runtime.h>

// WaveKANLinear: out[n,o] = sum_d mexhat((ln(x)[n,d]-t[o,d])/s[o,d]) * ww[o,d]
//                           + silu(sum_d x[n,d]*bw[o,d])
// N=8192, D=128, O=128, float32 in/out.
// R6: weights bf16-packed in LDS (8 B per (d,o), one ds_read_b64/thread/iter)
//     -> halves the 1.07 GB LDS weight stream that capped R5 at ~36us.
//     CHUNK=32 (4 chunks, 8 barriers). x stays fp32 [d][pair]{ln0,ln1,raw0,raw1}.

#define D_DIM 128
#define O_DIM 128
#define ROWS  16     // rows per block
#define BLOCK 1024   // 16 waves: o = tid&127, pair g = tid>>7 (2 rows each)
#define CHUNK 32     // d-rows staged per LDS chunk
#define NCHUNK (D_DIM / CHUNK)
#define XSTRIDE 9    // float4 stride for s_x rows (pads phase-1 write conflicts)

#define C1     0.72134752f   // 0.5*log2(e); exp(-z^2/2) = exp2(-C1*z^2)
#define SQRT_C 0.84932180f   // sqrt(C1)
#define WWK    1.2023651f    // MEX_C / C1, MEX_C = 2/(sqrt(3)*pi^0.25)
#define LOG2E  1.44269504f

typedef float v2f __attribute__((ext_vector_type(2)));

__device__ __forceinline__ unsigned bf16r(float f) {   // RNE round to bf16 bits
    unsigned u = __float_as_uint(f);
    return (u + 0x7fffu + ((u >> 16) & 1u)) >> 16;
}

// Prep: transpose weights to [d][o] uint2 { pack(t*is | is<<16), pack(ww*WWK | bw<<16) }
__global__ __launch_bounds__(256) void wavekan_prep(
    const float* __restrict__ scale,
    const float* __restrict__ trans,
    const float* __restrict__ ww,
    const float* __restrict__ bw,
    uint2* __restrict__ wsW)
{
    int idx = blockIdx.x * blockDim.x + threadIdx.x;   // = o*128 + d
    if (idx >= O_DIM * D_DIM) return;
    int o = idx >> 7;
    int d = idx & (D_DIM - 1);
    float sc = scale[idx];
    float sp = fmaxf(sc, 0.0f) + log1pf(__expf(-fabsf(sc)));  // stable softplus
    float is2 = SQRT_C / (sp + 0.1f);
    uint2 w;
    w.x = bf16r(trans[idx] * is2) | (bf16r(is2) << 16);
    w.y = bf16r(ww[idx] * WWK)    | (bf16r(bw[idx]) << 16);
    wsW[d * O_DIM + o] = w;
}

template<bool USE_WS>
__global__ __launch_bounds__(BLOCK, 8) void wavekan_main(
    const float* __restrict__ x,
    const float* __restrict__ scale,
    const float* __restrict__ trans,
    const float* __restrict__ ww,
    const float* __restrict__ bw,
    const float* __restrict__ gamma,
    const float* __restrict__ beta,
    const uint2* __restrict__ wsW,
    float* __restrict__ out,
    int N)
{
    // s_x[d * XSTRIDE + pair] = {ln_row0, ln_row1, raw_row0, raw_row1}
    __shared__ float4 s_x[D_DIM * XSTRIDE];          // 18 KB
    __shared__ uint4  s_w4[CHUNK * O_DIM / 2];       // 32 KB (uint2 pairs)

    const int tid  = threadIdx.x;
    const int row0 = blockIdx.x * ROWS;

    // ---- Phase 1: one wave per row (64 lanes x 2 elems), LayerNorm -> LDS ----
    {
        const int r  = tid >> 6;        // local row 0..15 == wave id
        const int j  = tid & 63;        // lane
        const int d0 = j * 2;           // 2 elems per lane
        const int grow = row0 + r;

        float2 v2 = make_float2(0.f, 0.f);
        if (grow < N)
            v2 = *reinterpret_cast<const float2*>(x + (size_t)grow * D_DIM + d0);

        float sum = v2.x + v2.y;
        float ssq = v2.x * v2.x + v2.y * v2.y;
        #pragma unroll
        for (int m = 1; m < 64; m <<= 1) {   // full-wave butterfly
            sum += __shfl_xor(sum, m, 64);
            ssq += __shfl_xor(ssq, m, 64);
        }
        const float mean = sum * (1.0f / D_DIM);
        const float var  = ssq * (1.0f / D_DIM) - mean * mean;
        const float rstd = rsqrtf(var + 1e-5f);

        float2 g2 = *reinterpret_cast<const float2*>(gamma + d0);
        float2 b2 = *reinterpret_cast<const float2*>(beta + d0);

        const int p  = r >> 1;          // pair index 0..7
        const int h  = r & 1;           // which row of the pair
        float* c0 = reinterpret_cast<float*>(&s_x[d0 * XSTRIDE + p]);
        float* c1 = reinterpret_cast<float*>(&s_x[(d0 + 1) * XSTRIDE + p]);
        c0[h]     = (v2.x - mean) * rstd * g2.x + b2.x;   // ln
        c0[2 + h] = v2.x;                                  // raw
        c1[h]     = (v2.y - mean) * rstd * g2.y + b2.y;
        c1[2 + h] = v2.y;
    }

    // ---- Phase 2: thread = column o x 2 rows; bf16 weights via LDS chunks ----
    const int o = tid & (O_DIM - 1);
    const int g = tid >> 7;  // pair 0..7
    const uint2* __restrict__ s_w = reinterpret_cast<const uint2*>(s_w4);

    v2f accw = {0.f, 0.f};
    v2f accb = {0.f, 0.f};

    if (USE_WS) {
        const uint4* __restrict__ wsWp = reinterpret_cast<const uint4*>(wsW);
        uint4 r0 = wsWp[tid];             // prefetch chunk 0 (2048 uint4 per chunk)
        uint4 r1 = wsWp[tid + BLOCK];
        for (int c = 0; c < NCHUNK; ++c) {
            __syncthreads();              // prev chunk compute done (+phase-1 at c=0)
            s_w4[tid]         = r0;
            s_w4[tid + BLOCK] = r1;
            if (c + 1 < NCHUNK) {         // prefetch next chunk during compute
                r0 = wsWp[(c + 1) * (CHUNK * O_DIM / 2) + tid];
                r1 = wsWp[(c + 1) * (CHUNK * O_DIM / 2) + tid + BLOCK];
            }
            __syncthreads();              // staging visible

            #pragma unroll 8
            for (int dl = 0; dl < CHUNK; ++dl) {
                uint2 wp  = s_w[dl * O_DIM + o];                 // ds_read_b64
                float4 xx = s_x[(c * CHUNK + dl) * XSTRIDE + g]; // broadcast b128
                float tis = __uint_as_float(wp.x << 16);
                float isv = __uint_as_float(wp.x & 0xffff0000u);
                float wwk = __uint_as_float(wp.y << 16);
                float bwv = __uint_as_float(wp.y & 0xffff0000u);
                v2f xln = {xx.x, xx.y};
                v2f xrw = {xx.z, xx.w};
                v2f u   = xln * isv - tis;       // pk_fma
                v2f q   = u * u;
                v2f e   = {__builtin_amdgcn_exp2f(-q.x),
                           __builtin_amdgcn_exp2f(-q.y)};
                accw += ((q - C1) * e) * wwk;
                accb += xrw * bwv;
            }
        }
    } else {
        __syncthreads();
        // fallback: direct global reads + on-the-fly softplus (slow, correct)
        for (int d = 0; d < D_DIM; ++d) {
            int idx = o * D_DIM + d;
            float sc = scale[idx];
            float sp = fmaxf(sc, 0.0f) + log1pf(__expf(-fabsf(sc)));
            float is  = SQRT_C / (sp + 0.1f);
            float tws = trans[idx] * is;
            float wwk = ww[idx] * WWK;
            float bwv = bw[idx];
            float4 xx = s_x[d * XSTRIDE + g];
            v2f xln = {xx.x, xx.y};
            v2f xrw = {xx.z, xx.w};
            v2f u   = xln * is - tws;
            v2f q   = u * u;
            v2f e   = {__builtin_amdgcn_exp2f(-q.x),
                       __builtin_amdgcn_exp2f(-q.y)};
            accw += ((q - C1) * e) * wwk;
            accb += xrw * bwv;
        }
    }

    // ---- Epilogue: out = wavelet + silu(base) ----
    {
        const int rr0 = row0 + g * 2;
        if (rr0 < N) {
            float sig0 = 1.0f / (1.0f + __builtin_amdgcn_exp2f(-LOG2E * accb.x));
            out[(size_t)rr0 * O_DIM + o] = accw.x + accb.x * sig0;
        }
        if (rr0 + 1 < N) {
            float sig1 = 1.0f / (1.0f + __builtin_amdgcn_exp2f(-LOG2E * accb.y));
            out[(size_t)(rr0 + 1) * O_DIM + o] = accw.y + accb.y * sig1;
        }
    }
}

extern "C" void kernel_launch(void* const* d_in, const int* in_sizes, int n_in,
                              void* d_out, int out_size, void* d_ws, size_t ws_size,
                              hipStream_t stream) {
    const float* x     = (const float*)d_in[0];
    const float* scale = (const float*)d_in[1];
    const float* trans = (const float*)d_in[2];
    const float* ww    = (const float*)d_in[3];
    const float* bw    = (const float*)d_in[4];
    const float* gamma = (const float*)d_in[5];
    const float* beta  = (const float*)d_in[6];
    float* out = (float*)d_out;

    const int N = in_sizes[0] / D_DIM;       // 8192
    const int grid = (N + ROWS - 1) / ROWS;  // 512

    const size_t ws_needed = (size_t)O_DIM * D_DIM * sizeof(uint2);  // 128 KB
    if (ws_size >= ws_needed) {
        wavekan_prep<<<(O_DIM * D_DIM + 255) / 256, 256, 0, stream>>>(
            scale, trans, ww, bw, (uint2*)d_ws);
        wavekan_main<true><<<grid, BLOCK, 0, stream>>>(
            x, scale, trans, ww, bw, gamma, beta, (const uint2*)d_ws, out, N);
    } else {
        wavekan_main<false><<<grid, BLOCK, 0, stream>>>(
            x, scale, trans, ww, bw, gamma, beta, nullptr, out, N);
    }
}